// Round 1
// baseline (229.227 us; speedup 1.0000x reference)
//
#include <hip/hip_runtime.h>
#include <cstdint>
#include <cstddef>

#define NEG_SLOPE 0.2f

// Problem sizes (fixed by setup_inputs)
#define BB 2
#define NN 2048
#define DD 512
#define HH 8
#define KK 64   // head dim

// Workspace layout (in floats unless noted)
// xh   : [B][H][N][64]  head-major projected features
// asrc : [B*H][N], adst : [B*H][N], amax : [B*H]
// maskw: [B*N][32] u64 bit-packed adjacency (after byte offset MASK_BYTE_OFF)
#define XH_OFF   0
#define XH_SZ    (BB*HH*NN*KK)            // 2097152
#define ASRC_OFF (XH_OFF + XH_SZ)         // 2097152
#define ADST_OFF (ASRC_OFF + BB*HH*NN)    // 2129920
#define AMAX_OFF (ADST_OFF + BB*HH*NN)    // 2162688
#define MASK_BYTE_OFF ((size_t)(AMAX_OFF + BB*HH) * 4)  // 8650816, 8B aligned

__device__ __forceinline__ float lrelu(float t) {
    return t > 0.f ? t : NEG_SLOPE * t;
}

// ---------------- Kernel 1: xp = x @ W_proj, stored as xh[b][h][n][kk] --------
__global__ __launch_bounds__(256) void k_proj(const float* __restrict__ x,
                                              const float* __restrict__ Wp,
                                              float* __restrict__ xh) {
    __shared__ float at[16][68];   // [k][m] transposed A tile
    __shared__ float bt[16][68];   // [k][o] B tile
    const int tid = threadIdx.x;
    const int m0  = blockIdx.x * 64;
    const int h   = blockIdx.y;        // o tile == head (64 cols)
    const int o0  = h * 64;
    const int ty = tid >> 4, tx = tid & 15;
    const int lrow = tid >> 2, lkq = tid & 3;   // A-tile load mapping
    const int brow = tid >> 4, boq = tid & 15;  // B-tile load mapping

    float acc[4][4] = {};

    for (int k0 = 0; k0 < DD; k0 += 16) {
        float4 av = *(const float4*)&x[(size_t)(m0 + lrow) * DD + k0 + lkq * 4];
        float4 bv = *(const float4*)&Wp[(size_t)(k0 + brow) * DD + o0 + boq * 4];
        __syncthreads();   // protect previous iteration's reads
        at[lkq * 4 + 0][lrow] = av.x;
        at[lkq * 4 + 1][lrow] = av.y;
        at[lkq * 4 + 2][lrow] = av.z;
        at[lkq * 4 + 3][lrow] = av.w;
        *(float4*)&bt[brow][boq * 4] = bv;
        __syncthreads();
#pragma unroll
        for (int kk = 0; kk < 16; ++kk) {
            float4 a = *(const float4*)&at[kk][ty * 4];
            float4 b = *(const float4*)&bt[kk][tx * 4];
            acc[0][0] += a.x * b.x; acc[0][1] += a.x * b.y; acc[0][2] += a.x * b.z; acc[0][3] += a.x * b.w;
            acc[1][0] += a.y * b.x; acc[1][1] += a.y * b.y; acc[1][2] += a.y * b.z; acc[1][3] += a.y * b.w;
            acc[2][0] += a.z * b.x; acc[2][1] += a.z * b.y; acc[2][2] += a.z * b.z; acc[2][3] += a.z * b.w;
            acc[3][0] += a.w * b.x; acc[3][1] += a.w * b.y; acc[3][2] += a.w * b.z; acc[3][3] += a.w * b.w;
        }
    }
#pragma unroll
    for (int ri = 0; ri < 4; ++ri) {
        int m = m0 + ty * 4 + ri;
        int b = m >> 11, n = m & (NN - 1);
        float4 o = make_float4(acc[ri][0], acc[ri][1], acc[ri][2], acc[ri][3]);
        *(float4*)&xh[(((size_t)(b * HH + h)) * NN + n) * KK + tx * 4] = o;
    }
}

// ---------------- Kernel 2a: a_src/a_dst per (b,h,n) --------------------------
__global__ __launch_bounds__(256) void k_attvec(const float* __restrict__ xh,
                                                const float* __restrict__ Watt,
                                                float* __restrict__ asrc,
                                                float* __restrict__ adst) {
    __shared__ float wsd[128];
    const int tid = threadIdx.x;
    const int idx = blockIdx.x * 256 + tid;          // (b*H+h)*N + n
    const int h = (idx >> 11) & (HH - 1);
    if (tid < 128) wsd[tid] = Watt[h * 128 + tid];
    __syncthreads();
    const float* row = &xh[(size_t)idx * KK];
    float s1 = 0.f, s2 = 0.f;
#pragma unroll
    for (int q = 0; q < 16; ++q) {
        float4 v  = *(const float4*)&row[q * 4];
        float4 w1 = *(const float4*)&wsd[q * 4];
        float4 w2 = *(const float4*)&wsd[64 + q * 4];
        s1 += v.x * w1.x + v.y * w1.y + v.z * w1.z + v.w * w1.w;
        s2 += v.x * w2.x + v.y * w2.y + v.z * w2.z + v.w * w2.w;
    }
    asrc[idx] = s1;
    adst[idx] = s2;
}

// ---------------- Kernel 2b: amax[b*H+h] = max_n a_dst ------------------------
__global__ __launch_bounds__(256) void k_amax(const float* __restrict__ adst,
                                              float* __restrict__ amax) {
    __shared__ float red[256];
    const int bh = blockIdx.x, tid = threadIdx.x;
    float m = -1e30f;
    for (int n = tid; n < NN; n += 256) m = fmaxf(m, adst[bh * NN + n]);
    red[tid] = m;
    __syncthreads();
    for (int s = 128; s > 0; s >>= 1) {
        if (tid < s) red[tid] = fmaxf(red[tid], red[tid + s]);
        __syncthreads();
    }
    if (tid == 0) amax[bh] = red[0];
}

// ---------------- Kernel 2c: pack adjacency to bits ---------------------------
__global__ __launch_bounds__(256) void k_mask(const int* __restrict__ A,
                                              unsigned long long* __restrict__ mw) {
    const int tid = threadIdx.x;
    const int wave = tid >> 6, lane = tid & 63;
    const int r = blockIdx.x * 4 + wave;  // b*N + n, 0..4095
    const int* row = &A[(size_t)r * NN];
#pragma unroll 4
    for (int c = 0; c < 32; ++c) {
        unsigned long long m = __ballot(row[c * 64 + lane] != 0);
        if (lane == 0) mw[(size_t)r * 32 + c] = m;
    }
}

// ---------------- Kernel 3: masked softmax + PV -------------------------------
// Block: 256 threads, handles (b, h, 64-row i-tile). acc tile 64i x 64k.
__global__ __launch_bounds__(256) void k_attn(const float* __restrict__ xh,
                                              const float* __restrict__ asrc,
                                              const float* __restrict__ adst,
                                              const float* __restrict__ amax,
                                              const unsigned long long* __restrict__ mw,
                                              const float* __restrict__ batt,
                                              float* __restrict__ out) {
    __shared__ float wT[64][68];     // transposed weights [j][i]
    __shared__ float vt[64][68];     // V tile [j][k]
    __shared__ float asl[64], Ml[64], adl[64];
    __shared__ unsigned long long mwl[64];
    __shared__ float wsr[64][17];
    __shared__ float wsinv[64];

    const int tid = threadIdx.x;
    const int bid = blockIdx.x;
    const int bh = bid >> 5;           // (b*H+h)
    const int it = bid & 31;
    const int b = bh >> 3, h = bh & (HH - 1);
    const int i0 = it * 64;
    const float bb = batt[h];
    const float am = amax[bh];

    if (tid < 64) {
        float as = asrc[bh * NN + i0 + tid];
        asl[tid] = as;
        Ml[tid] = lrelu(as + am + bb);   // upper bound of row max -> safe shift
    }
    const int ty = tid >> 4, tx = tid & 15;
    float acc[4][4] = {};
    float wsp[4] = {};
    const float* vbase = &xh[(size_t)bh * NN * KK];

    for (int c = 0; c < 32; ++c) {
        const int j0 = c * 64;
        __syncthreads();   // protect previous compute phase
        if (tid < 64) {
            adl[tid] = adst[bh * NN + j0 + tid];
            mwl[tid] = mw[((size_t)(b * NN + i0 + tid)) * 32 + c];
        }
#pragma unroll
        for (int t = 0; t < 4; ++t) {
            int li = tid + t * 256;
            int row = li >> 4, q = li & 15;
            *(float4*)&vt[row][q * 4] = *(const float4*)&vbase[(size_t)(j0 + row) * KK + q * 4];
        }
        __syncthreads();
        // weight tile
#pragma unroll
        for (int ri = 0; ri < 4; ++ri) {
            int i = ty * 4 + ri;
            float as = asl[i], Mi = Ml[i];
            unsigned long long m = mwl[i];
#pragma unroll
            for (int ci = 0; ci < 4; ++ci) {
                int j = tx * 4 + ci;
                float t2 = as + adl[j] + bb;
                float s = lrelu(t2);
                float w = ((m >> j) & 1ULL) ? __expf(s - Mi) : 0.f;
                wT[j][i] = w;
                wsp[ri] += w;
            }
        }
        __syncthreads();
        // PV accumulate
#pragma unroll 8
        for (int jj = 0; jj < 64; ++jj) {
            float4 a = *(const float4*)&wT[jj][ty * 4];
            float4 v = *(const float4*)&vt[jj][tx * 4];
            acc[0][0] += a.x * v.x; acc[0][1] += a.x * v.y; acc[0][2] += a.x * v.z; acc[0][3] += a.x * v.w;
            acc[1][0] += a.y * v.x; acc[1][1] += a.y * v.y; acc[1][2] += a.y * v.z; acc[1][3] += a.y * v.w;
            acc[2][0] += a.z * v.x; acc[2][1] += a.z * v.y; acc[2][2] += a.z * v.z; acc[2][3] += a.z * v.w;
            acc[3][0] += a.w * v.x; acc[3][1] += a.w * v.y; acc[3][2] += a.w * v.z; acc[3][3] += a.w * v.w;
        }
    }

    // row-sum reduction for softmax denominator
    __syncthreads();
#pragma unroll
    for (int ri = 0; ri < 4; ++ri) wsr[ty * 4 + ri][tx] = wsp[ri];
    __syncthreads();
    if (tid < 64) {
        float s = 0.f;
#pragma unroll
        for (int t = 0; t < 16; ++t) s += wsr[tid][t];
        wsinv[tid] = 1.f / fmaxf(s, 1e-30f);
    }
    __syncthreads();
#pragma unroll
    for (int ri = 0; ri < 4; ++ri) {
        int i = ty * 4 + ri;
        float inv = wsinv[i];
        float4 o;
        o.x = fmaxf(acc[ri][0] * inv, 0.f);
        o.y = fmaxf(acc[ri][1] * inv, 0.f);
        o.z = fmaxf(acc[ri][2] * inv, 0.f);
        o.w = fmaxf(acc[ri][3] * inv, 0.f);
        *(float4*)&out[((size_t)(b * NN + i0 + i)) * DD + h * KK + tx * 4] = o;
    }
}

extern "C" void kernel_launch(void* const* d_in, const int* in_sizes, int n_in,
                              void* d_out, int out_size, void* d_ws, size_t ws_size,
                              hipStream_t stream) {
    const float* x    = (const float*)d_in[0];
    const int*   A    = (const int*)d_in[1];
    const float* Wp   = (const float*)d_in[2];
    const float* Watt = (const float*)d_in[3];
    const float* batt = (const float*)d_in[4];
    float* out = (float*)d_out;

    float* ws = (float*)d_ws;
    float* xh   = ws + XH_OFF;
    float* asrc = ws + ASRC_OFF;
    float* adst = ws + ADST_OFF;
    float* amax = ws + AMAX_OFF;
    unsigned long long* mw = (unsigned long long*)((char*)d_ws + MASK_BYTE_OFF);

    // 1) projection GEMM -> xh (head-major)
    k_proj<<<dim3(64, 8), 256, 0, stream>>>(x, Wp, xh);
    // 2) per-node attention scalars + global dst max + packed mask
    k_attvec<<<dim3(128), 256, 0, stream>>>(xh, Watt, asrc, adst);
    k_amax<<<dim3(16), 256, 0, stream>>>(adst, amax);
    k_mask<<<dim3(1024), 256, 0, stream>>>(A, mw);
    // 3) masked softmax + PV + relu
    k_attn<<<dim3(BB * HH * 32), 256, 0, stream>>>(xh, asrc, adst, amax, mw, batt, out);
}

// Round 2
// 116.054 us; speedup vs baseline: 1.9752x; 1.9752x over previous
//
#include <hip/hip_runtime.h>
#include <cstdint>
#include <cstddef>

#define NEG_SLOPE 0.2f

// Problem sizes (fixed by setup_inputs)
#define BB 2
#define NN 2048
#define DD 512
#define HH 8
#define KK 64   // head dim

typedef _Float16 half8 __attribute__((ext_vector_type(8)));
typedef _Float16 half4 __attribute__((ext_vector_type(4)));
typedef float floatx4 __attribute__((ext_vector_type(4)));

// Workspace layout (floats unless noted)
#define XH_OFF   0
#define XH_SZ    (BB*HH*NN*KK)            // 2097152 floats
#define ASRC_OFF (XH_OFF + XH_SZ)
#define ADST_OFF (ASRC_OFF + BB*HH*NN)
#define AMAX_OFF (ADST_OFF + BB*HH*NN)
#define MASK_BYTE_OFF ((size_t)(AMAX_OFF + BB*HH) * 4)              // 8650816 B
#define XHT_BYTE_OFF  (MASK_BYTE_OFF + (size_t)BB*NN*32*8)          // +1 MB -> 9699392 B
// xhT16: [B*H][64][NN] _Float16 = 4 MB

__device__ __forceinline__ float lrelu(float t) {
    return fmaxf(t, NEG_SLOPE * t);
}

// ---------------- Kernel 1: xp = x @ W_proj -> xh[bh][n][kk] (f32) + xhT16[bh][kk][n] (f16)
__global__ __launch_bounds__(256) void k_proj(const float* __restrict__ x,
                                              const float* __restrict__ Wp,
                                              float* __restrict__ xh,
                                              _Float16* __restrict__ xhT) {
    __shared__ float at[16][68];   // [k][m] transposed A tile
    __shared__ float bt[16][68];   // [k][o] B tile
    const int tid = threadIdx.x;
    const int m0  = blockIdx.x * 64;
    const int h   = blockIdx.y;
    const int o0  = h * 64;
    const int ty = tid >> 4, tx = tid & 15;
    const int lrow = tid >> 2, lkq = tid & 3;
    const int brow = tid >> 4, boq = tid & 15;

    float acc[4][4] = {};

    for (int k0 = 0; k0 < DD; k0 += 16) {
        float4 av = *(const float4*)&x[(size_t)(m0 + lrow) * DD + k0 + lkq * 4];
        float4 bv = *(const float4*)&Wp[(size_t)(k0 + brow) * DD + o0 + boq * 4];
        __syncthreads();
        at[lkq * 4 + 0][lrow] = av.x;
        at[lkq * 4 + 1][lrow] = av.y;
        at[lkq * 4 + 2][lrow] = av.z;
        at[lkq * 4 + 3][lrow] = av.w;
        *(float4*)&bt[brow][boq * 4] = bv;
        __syncthreads();
#pragma unroll
        for (int kk = 0; kk < 16; ++kk) {
            float4 a = *(const float4*)&at[kk][ty * 4];
            float4 b = *(const float4*)&bt[kk][tx * 4];
            acc[0][0] += a.x * b.x; acc[0][1] += a.x * b.y; acc[0][2] += a.x * b.z; acc[0][3] += a.x * b.w;
            acc[1][0] += a.y * b.x; acc[1][1] += a.y * b.y; acc[1][2] += a.y * b.z; acc[1][3] += a.y * b.w;
            acc[2][0] += a.z * b.x; acc[2][1] += a.z * b.y; acc[2][2] += a.z * b.z; acc[2][3] += a.z * b.w;
            acc[3][0] += a.w * b.x; acc[3][1] += a.w * b.y; acc[3][2] += a.w * b.z; acc[3][3] += a.w * b.w;
        }
    }
    const int b = (m0 + ty * 4) >> 11;
    const int n0 = (m0 + ty * 4) & (NN - 1);
#pragma unroll
    for (int ri = 0; ri < 4; ++ri) {
        float4 o = make_float4(acc[ri][0], acc[ri][1], acc[ri][2], acc[ri][3]);
        *(float4*)&xh[(((size_t)(b * HH + h)) * NN + n0 + ri) * KK + tx * 4] = o;
    }
    // transposed fp16 copy: xhT[(bh*64 + kk)][n], thread has 4 consecutive n per kk
#pragma unroll
    for (int ci = 0; ci < 4; ++ci) {
        half4 hv;
        hv[0] = (_Float16)acc[0][ci];
        hv[1] = (_Float16)acc[1][ci];
        hv[2] = (_Float16)acc[2][ci];
        hv[3] = (_Float16)acc[3][ci];
        *(half4*)&xhT[((size_t)(b * HH + h) * 64 + tx * 4 + ci) * NN + n0] = hv;
    }
}

// ---------------- Kernel 2a: a_src/a_dst per (b,h,n) --------------------------
__global__ __launch_bounds__(256) void k_attvec(const float* __restrict__ xh,
                                                const float* __restrict__ Watt,
                                                float* __restrict__ asrc,
                                                float* __restrict__ adst) {
    __shared__ float wsd[128];
    const int tid = threadIdx.x;
    const int idx = blockIdx.x * 256 + tid;
    const int h = (idx >> 11) & (HH - 1);
    if (tid < 128) wsd[tid] = Watt[h * 128 + tid];
    __syncthreads();
    const float* row = &xh[(size_t)idx * KK];
    float s1 = 0.f, s2 = 0.f;
#pragma unroll
    for (int q = 0; q < 16; ++q) {
        float4 v  = *(const float4*)&row[q * 4];
        float4 w1 = *(const float4*)&wsd[q * 4];
        float4 w2 = *(const float4*)&wsd[64 + q * 4];
        s1 += v.x * w1.x + v.y * w1.y + v.z * w1.z + v.w * w1.w;
        s2 += v.x * w2.x + v.y * w2.y + v.z * w2.z + v.w * w2.w;
    }
    asrc[idx] = s1;
    adst[idx] = s2;
}

// ---------------- Kernel 2b: amax[b*H+h] = max_n a_dst ------------------------
__global__ __launch_bounds__(256) void k_amax(const float* __restrict__ adst,
                                              float* __restrict__ amax) {
    __shared__ float red[256];
    const int bh = blockIdx.x, tid = threadIdx.x;
    float m = -1e30f;
    for (int n = tid; n < NN; n += 256) m = fmaxf(m, adst[bh * NN + n]);
    red[tid] = m;
    __syncthreads();
    for (int s = 128; s > 0; s >>= 1) {
        if (tid < s) red[tid] = fmaxf(red[tid], red[tid + s]);
        __syncthreads();
    }
    if (tid == 0) amax[bh] = red[0];
}

// ---------------- Kernel 2c: pack adjacency to bits ---------------------------
__global__ __launch_bounds__(256) void k_mask(const int* __restrict__ A,
                                              unsigned long long* __restrict__ mw) {
    const int tid = threadIdx.x;
    const int wave = tid >> 6, lane = tid & 63;
    const int r = blockIdx.x * 4 + wave;
    const int* row = &A[(size_t)r * NN];
#pragma unroll 4
    for (int c = 0; c < 32; ++c) {
        unsigned long long m = __ballot(row[c * 64 + lane] != 0);
        if (lane == 0) mw[(size_t)r * 32 + c] = m;
    }
}

// ---------------- Kernel 3: masked softmax + PV via MFMA ----------------------
// Block: 256 thr / 4 waves, handles (bh, 64-row i-tile). Wave w owns rows w*16..+16.
// Scores computed per-lane directly in the MFMA A-fragment layout.
#define VS 72   // LDS row stride (ushorts) for the transposed V tile
__global__ __launch_bounds__(256) void k_attn(const _Float16* __restrict__ xhT,
                                              const float* __restrict__ asrc,
                                              const float* __restrict__ adst,
                                              const float* __restrict__ amax,
                                              const unsigned long long* __restrict__ mw,
                                              const float* __restrict__ batt,
                                              float* __restrict__ out) {
    __shared__ _Float16 vt[64 * VS];       // V tile transposed: [kk][j], stride VS
    __shared__ float adl[64];
    __shared__ unsigned long long mwl[64];
    __shared__ float wsl[64];

    const int tid = threadIdx.x;
    const int bid = blockIdx.x;
    const int bh = bid >> 5;
    const int it = bid & 31;
    const int b = bh >> 3, h = bh & (HH - 1);
    const int i0 = it * 64;
    const int w = tid >> 6;                // wave id
    const int l = tid & 63;                // lane
    const int li = l & 15, p = l >> 4;

    const float bb = batt[h];
    const float am = amax[bh];
    const int i = i0 + w * 16 + li;        // this lane's score row (A-frag row)
    const float asb = asrc[bh * NN + i] + bb;
    const float Mi = lrelu(asb + am);      // upper bound of row max (safe shift)
    float dsum = 0.f;
    floatx4 acc[4] = {{0.f,0.f,0.f,0.f},{0.f,0.f,0.f,0.f},{0.f,0.f,0.f,0.f},{0.f,0.f,0.f,0.f}};

    const _Float16* vsrc = xhT + (size_t)bh * 64 * NN;
    const int skk = tid >> 3;              // staging: rows 0..31 (+32 second pass)
    const int sjc = (tid & 7) * 8;         // 8 f16 = 16B chunk

    for (int c = 0; c < 32; ++c) {
        const int j0 = c * 64;
        __syncthreads();                   // protect previous iteration's reads
        if (tid < 64) {
            adl[tid] = adst[bh * NN + j0 + tid];
            mwl[tid] = mw[((size_t)(b * NN + i0 + tid)) * 32 + c];
        }
        *(uint4*)&vt[skk * VS + sjc]        = *(const uint4*)&vsrc[(size_t)skk * NN + j0 + sjc];
        *(uint4*)&vt[(skk + 32) * VS + sjc] = *(const uint4*)&vsrc[(size_t)(skk + 32) * NN + j0 + sjc];
        __syncthreads();

        const unsigned long long mword = mwl[w * 16 + li];
#pragma unroll
        for (int js = 0; js < 2; ++js) {
            const int shbase = js * 32 + p * 8;   // first j (of 8) this lane covers
            float4 A0 = *(const float4*)&adl[shbase];
            float4 A1 = *(const float4*)&adl[shbase + 4];
            const unsigned m8 = (unsigned)(mword >> shbase) & 0xFFu;
            float sv[8] = {A0.x, A0.y, A0.z, A0.w, A1.x, A1.y, A1.z, A1.w};
            half8 af;
#pragma unroll
            for (int e = 0; e < 8; ++e) {
                float t = asb + sv[e];
                float s = fmaxf(t, NEG_SLOPE * t);          // leaky relu
                float wv = ((m8 >> e) & 1u) ? __expf(s - Mi) : 0.f;
                _Float16 hh = (_Float16)wv;
                af[e] = hh;
                dsum += (float)hh;                          // consistent denominator
            }
#pragma unroll
            for (int ct = 0; ct < 4; ++ct) {
                const half8 bf = *(const half8*)&vt[(ct * 16 + li) * VS + shbase];
                acc[ct] = __builtin_amdgcn_mfma_f32_16x16x32_f16(af, bf, acc[ct], 0, 0, 0);
            }
        }
    }

    // row-sum across the 4 lane-groups holding the same row
    dsum += __shfl_xor(dsum, 16, 64);
    dsum += __shfl_xor(dsum, 32, 64);
    __syncthreads();
    if (l < 16) wsl[w * 16 + l] = dsum;
    __syncthreads();

    float inv[4];
#pragma unroll
    for (int r = 0; r < 4; ++r)
        inv[r] = 1.f / fmaxf(wsl[w * 16 + p * 4 + r], 1e-30f);

#pragma unroll
    for (int ct = 0; ct < 4; ++ct) {
#pragma unroll
        for (int r = 0; r < 4; ++r) {
            const int irow = i0 + w * 16 + p * 4 + r;       // C-frag: row=(l>>4)*4+reg
            const int kk = ct * 16 + li;                    // C-frag: col=l&15
            out[((size_t)(b * NN + irow)) * DD + h * KK + kk] =
                fmaxf(acc[ct][r] * inv[r], 0.f);
        }
    }
}

extern "C" void kernel_launch(void* const* d_in, const int* in_sizes, int n_in,
                              void* d_out, int out_size, void* d_ws, size_t ws_size,
                              hipStream_t stream) {
    const float* x    = (const float*)d_in[0];
    const int*   A    = (const int*)d_in[1];
    const float* Wp   = (const float*)d_in[2];
    const float* Watt = (const float*)d_in[3];
    const float* batt = (const float*)d_in[4];
    float* out = (float*)d_out;

    float* ws = (float*)d_ws;
    float* xh   = ws + XH_OFF;
    float* asrc = ws + ASRC_OFF;
    float* adst = ws + ADST_OFF;
    float* amax = ws + AMAX_OFF;
    unsigned long long* mwp = (unsigned long long*)((char*)d_ws + MASK_BYTE_OFF);
    _Float16* xhT = (_Float16*)((char*)d_ws + XHT_BYTE_OFF);

    k_proj<<<dim3(64, 8), 256, 0, stream>>>(x, Wp, xh, xhT);
    k_attvec<<<dim3(128), 256, 0, stream>>>(xh, Watt, asrc, adst);
    k_amax<<<dim3(16), 256, 0, stream>>>(adst, amax);
    k_mask<<<dim3(1024), 256, 0, stream>>>(A, mwp);
    k_attn<<<dim3(BB * HH * 32), 256, 0, stream>>>(xhT, asrc, adst, amax, mwp, batt, out);
}

// Round 4
// 87.609 us; speedup vs baseline: 2.6165x; 1.3247x over previous
//
#include <hip/hip_runtime.h>
#include <cstdint>
#include <cstddef>

#define NEG_SLOPE 0.2f

// Problem sizes (fixed by setup_inputs)
#define BB 2
#define NN 2048
#define DD 512
#define HH 8
#define KK 64   // head dim

typedef _Float16 half8 __attribute__((ext_vector_type(8)));
typedef _Float16 half4 __attribute__((ext_vector_type(4)));
typedef __fp16 fp16x2 __attribute__((ext_vector_type(2)));
typedef float floatx4 __attribute__((ext_vector_type(4)));

// Workspace layout (bytes)
#define X16_OFF   ((size_t)0)            // x16: 2,097,152 f16 = 4 MB
#define WT_OFF    ((size_t)4194304)      // WpT16: 262144 f16 = 512 KB
#define XHT_OFF   ((size_t)4718592)      // xhT: [B*H][64][2048] f16 = 4 MB
#define ASRC_OFF  ((size_t)8912896)      // 32768 f32
#define ADST_OFF  ((size_t)9043968)      // 32768 f32
#define AMAX_OFF  ((size_t)9175040)      // 16 f32 (+pad)
#define MW_OFF    ((size_t)9175104)      // mwT: [B][32][2048] u64 = 1 MB

// ---------------- Kernel 0: convert x -> f16, transpose W_proj -> f16 ---------
__global__ __launch_bounds__(256) void k_prep(const float* __restrict__ x,
                                              const float* __restrict__ Wp,
                                              _Float16* __restrict__ x16,
                                              _Float16* __restrict__ WT) {
    __shared__ float tile[64][65];
    const int tid = threadIdx.x;
    const int bi = blockIdx.x;
    if (bi < 512) {                       // x conversion: 512*256*16 = 2,097,152
        const size_t base = (size_t)bi * 4096 + tid * 16;
#pragma unroll
        for (int q = 0; q < 2; ++q) {
            float4 v0 = *(const float4*)&x[base + q * 8];
            float4 v1 = *(const float4*)&x[base + q * 8 + 4];
            half8 hv;
            hv[0] = (_Float16)v0.x; hv[1] = (_Float16)v0.y;
            hv[2] = (_Float16)v0.z; hv[3] = (_Float16)v0.w;
            hv[4] = (_Float16)v1.x; hv[5] = (_Float16)v1.y;
            hv[6] = (_Float16)v1.z; hv[7] = (_Float16)v1.w;
            *(half8*)&x16[base + q * 8] = hv;
        }
    } else {                              // W transpose: 64 blocks of 64x64
        const int wb = bi - 512;
        const int d0 = (wb >> 3) * 64, o0 = (wb & 7) * 64;
        const int r = tid >> 2, cq = tid & 3;
#pragma unroll
        for (int qq = 0; qq < 4; ++qq) {
            float4 v = *(const float4*)&Wp[(size_t)(d0 + r) * DD + o0 + cq * 16 + qq * 4];
            tile[r][cq * 16 + qq * 4 + 0] = v.x;
            tile[r][cq * 16 + qq * 4 + 1] = v.y;
            tile[r][cq * 16 + qq * 4 + 2] = v.z;
            tile[r][cq * 16 + qq * 4 + 3] = v.w;
        }
        __syncthreads();
#pragma unroll
        for (int qq = 0; qq < 2; ++qq) {
            half8 hv;
#pragma unroll
            for (int e = 0; e < 8; ++e) hv[e] = (_Float16)tile[cq * 16 + qq * 8 + e][r];
            *(half8*)&WT[(size_t)(o0 + r) * DD + d0 + cq * 16 + qq * 8] = hv;
        }
    }
}

// ---------------- Kernel 1: proj GEMM (f16 MFMA) + fused a_src/a_dst ----------
// Grid (64 m-tiles, 8 heads), 256 thr / 4 waves. Wave owns 16 rows x 64 cols.
__global__ __launch_bounds__(256) void k_proj(const _Float16* __restrict__ x16,
                                              const _Float16* __restrict__ WT,
                                              const float* __restrict__ Watt,
                                              _Float16* __restrict__ xhT,
                                              float* __restrict__ asrc,
                                              float* __restrict__ adst) {
    const int tid = threadIdx.x;
    const int m0 = blockIdx.x * 64;
    const int h  = blockIdx.y;
    const int w = tid >> 6, l = tid & 63, li = l & 15, p = l >> 4;
    const _Float16* arow  = x16 + (size_t)(m0 + w * 16 + li) * DD + p * 8;
    const _Float16* bbase = WT + ((size_t)h * 64 + li) * DD + p * 8;
    floatx4 acc[4] = {};
    for (int k0 = 0; k0 < DD; k0 += 32) {
        half8 a = *(const half8*)(arow + k0);
#pragma unroll
        for (int ct = 0; ct < 4; ++ct) {
            half8 bfr = *(const half8*)(bbase + (size_t)ct * 16 * DD + k0);
            acc[ct] = __builtin_amdgcn_mfma_f32_16x16x32_f16(a, bfr, acc[ct], 0, 0, 0);
        }
    }
    const int b = m0 >> 11, n0 = m0 & (NN - 1);
    const int bh = b * HH + h;
    // xhT[bh][kk][n]: lane writes 4 consecutive n (rows p*4+r) per kk col
#pragma unroll
    for (int ct = 0; ct < 4; ++ct) {
        half4 hv;
#pragma unroll
        for (int r = 0; r < 4; ++r) hv[r] = (_Float16)acc[ct][r];
        *(half4*)&xhT[((size_t)bh * 64 + ct * 16 + li) * NN + n0 + w * 16 + p * 4] = hv;
    }
    // fused a_src/a_dst: this block holds the full 64-col head reduction
    float w1[4], w2[4];
#pragma unroll
    for (int ct = 0; ct < 4; ++ct) {
        w1[ct] = Watt[h * 128 + ct * 16 + li];
        w2[ct] = Watt[h * 128 + 64 + ct * 16 + li];
    }
#pragma unroll
    for (int r = 0; r < 4; ++r) {
        float s1 = 0.f, s2 = 0.f;
#pragma unroll
        for (int ct = 0; ct < 4; ++ct) { s1 += acc[ct][r] * w1[ct]; s2 += acc[ct][r] * w2[ct]; }
#pragma unroll
        for (int d = 1; d < 16; d <<= 1) { s1 += __shfl_xor(s1, d, 64); s2 += __shfl_xor(s2, d, 64); }
        if (li == 0) {
            const int n = n0 + w * 16 + p * 4 + r;
            asrc[bh * NN + n] = s1;
            adst[bh * NN + n] = s2;
        }
    }
}

// ---------------- Kernel 2: amax[bh] = max_n a_dst ----------------------------
__global__ __launch_bounds__(256) void k_amax(const float* __restrict__ adst,
                                              float* __restrict__ amax) {
    __shared__ float red[256];
    const int bh = blockIdx.x, tid = threadIdx.x;
    float m = -1e30f;
    for (int n = tid; n < NN; n += 256) m = fmaxf(m, adst[bh * NN + n]);
    red[tid] = m;
    __syncthreads();
    for (int s = 128; s > 0; s >>= 1) {
        if (tid < s) red[tid] = fmaxf(red[tid], red[tid + s]);
        __syncthreads();
    }
    if (tid == 0) amax[bh] = red[0];
}

// ---------------- Kernel 3: pack adjacency to bits, transposed [b][c][n] ------
__global__ __launch_bounds__(256) void k_mask(const int* __restrict__ A,
                                              unsigned long long* __restrict__ mwT) {
    __shared__ unsigned long long mwt[32][8];
    const int tid = threadIdx.x;
    const int w = tid >> 6, lane = tid & 63;
    const int bi = blockIdx.x;
    const int b = bi >> 8, n0 = (bi & 255) * 8;
#pragma unroll
    for (int rr = 0; rr < 2; ++rr) {
        const int rl = w * 2 + rr;
        const int* Arow = A + ((size_t)b * NN + n0 + rl) * NN;
#pragma unroll 4
        for (int c = 0; c < 32; ++c) {
            unsigned long long m = __ballot(Arow[c * 64 + lane] != 0);
            if (lane == 0) mwt[c][rl] = m;
        }
    }
    __syncthreads();
    const int c = tid >> 3, rl = tid & 7;
    mwT[((size_t)b * 32 + c) * NN + n0 + rl] = mwt[c][rl];
}

// ---------------- Kernel 4: masked softmax + PV via MFMA ----------------------
// 512 thr / 8 waves: group g = w>>2 handles c ≡ g (mod 2); wave ws=w&3 owns 16 rows.
// V tile XOR-swizzled (conflict-free b128); denominator via ones-MFMA.
__global__ __launch_bounds__(512) void k_attn(const _Float16* __restrict__ xhT,
                                              const float* __restrict__ asrc,
                                              const float* __restrict__ adst,
                                              const float* __restrict__ amax,
                                              const unsigned long long* __restrict__ mwT,
                                              const float* __restrict__ batt,
                                              float* __restrict__ out) {
    __shared__ __align__(16) _Float16 vt[2][4096];        // 2 x 8KB V tiles
    __shared__ float adl[2][64];
    __shared__ unsigned long long mwl[2][64];
    __shared__ float accd_s[4][16];

    const int tid = threadIdx.x;
    const int w = tid >> 6, g = w >> 2, ws = w & 3;
    const int l = tid & 63, li = l & 15, p = l >> 4;
    const int gt = tid & 255;
    const int bid = blockIdx.x;
    const int bh = bid >> 5, it = bid & 31;
    const int b = bh >> 3, h = bh & (HH - 1);
    const int i0 = it * 64;

    const float bb = batt[h];
    const float am = amax[bh];
    const int i = i0 + ws * 16 + li;
    const float asb = asrc[bh * NN + i] + bb;
    const float tb = asb + am;
    const float Mi = fmaxf(tb, NEG_SLOPE * tb);           // row-max upper bound
    floatx4 acc[4] = {};
    floatx4 accd = {};
    half8 ones;
#pragma unroll
    for (int e = 0; e < 8; ++e) ones[e] = (_Float16)1.0f;

    const _Float16* vsrc = xhT + (size_t)bh * 64 * NN;
    char* vtg = (char*)&vt[g][0];
    const int srow = gt >> 3, sq = gt & 7;
    char* wdst0 = vtg + srow * 128 + ((sq * 16) ^ ((srow & 7) << 4));
    char* wdst1 = vtg + (srow + 32) * 128 + ((sq * 16) ^ ((srow & 7) << 4));
    const _Float16* src0 = vsrc + (size_t)srow * NN + sq * 8;
    const _Float16* src1 = vsrc + (size_t)(srow + 32) * NN + sq * 8;

    for (int ci = 0; ci < 16; ++ci) {
        const int c = ci * 2 + g;
        const int j0 = c * 64;
        __syncthreads();
        if (gt < 64) {
            adl[g][gt] = adst[bh * NN + j0 + gt];
            mwl[g][gt] = mwT[((size_t)b * 32 + c) * NN + i0 + gt];
        }
        *(uint4*)wdst0 = *(const uint4*)(src0 + j0);
        *(uint4*)wdst1 = *(const uint4*)(src1 + j0);
        __syncthreads();

        const unsigned long long mword = mwl[g][ws * 16 + li];
#pragma unroll
        for (int js = 0; js < 2; ++js) {
            const int shbase = js * 32 + p * 8;
            float4 A0 = *(const float4*)&adl[g][shbase];
            float4 A1 = *(const float4*)&adl[g][shbase + 4];
            const unsigned m8 = (unsigned)(mword >> shbase) & 0xFFu;
            float sv[8] = {A0.x, A0.y, A0.z, A0.w, A1.x, A1.y, A1.z, A1.w};
            float wv[8];
#pragma unroll
            for (int e = 0; e < 8; ++e) {
                float t = asb + sv[e];
                float s = fmaxf(t, NEG_SLOPE * t);
                float ev = __expf(s - Mi);
                wv[e] = ((m8 >> e) & 1u) ? ev : 0.f;
            }
            union { fp16x2 h2[4]; half8 h8; } u;
            u.h2[0] = __builtin_amdgcn_cvt_pkrtz(wv[0], wv[1]);
            u.h2[1] = __builtin_amdgcn_cvt_pkrtz(wv[2], wv[3]);
            u.h2[2] = __builtin_amdgcn_cvt_pkrtz(wv[4], wv[5]);
            u.h2[3] = __builtin_amdgcn_cvt_pkrtz(wv[6], wv[7]);
            const half8 af = u.h8;
            accd = __builtin_amdgcn_mfma_f32_16x16x32_f16(af, ones, accd, 0, 0, 0);
#pragma unroll
            for (int ct = 0; ct < 4; ++ct) {
                const half8 bf = *(const half8*)(vtg + (ct * 16 + li) * 128 +
                                                 ((js * 64 + p * 16) ^ ((li & 7) << 4)));
                acc[ct] = __builtin_amdgcn_mfma_f32_16x16x32_f16(af, bf, acc[ct], 0, 0, 0);
            }
        }
    }

    // combine the two c-groups' partials (acc + denominators) via LDS
    __syncthreads();
    float* accs = (float*)&vt[0][0];                      // 16KB, reuse V tiles
    if (g == 1) {
#pragma unroll
        for (int ct = 0; ct < 4; ++ct)
#pragma unroll
            for (int r = 0; r < 4; ++r)
                accs[(ws * 16 + p * 4 + r) * 64 + ct * 16 + li] = acc[ct][r];
        if (li == 0) {
#pragma unroll
            for (int r = 0; r < 4; ++r) accd_s[ws][p * 4 + r] = accd[r];
        }
    }
    __syncthreads();
    if (g == 0) {
#pragma unroll
        for (int r = 0; r < 4; ++r) {
            const float d = accd[r] + accd_s[ws][p * 4 + r];
            const float inv = 1.f / fmaxf(d, 1e-30f);
            const int irow = i0 + ws * 16 + p * 4 + r;
            float* orow = out + ((size_t)b * NN + irow) * DD + h * KK;
#pragma unroll
            for (int ct = 0; ct < 4; ++ct) {
                const float v = (acc[ct][r] + accs[(ws * 16 + p * 4 + r) * 64 + ct * 16 + li]) * inv;
                orow[ct * 16 + li] = fmaxf(v, 0.f);
            }
        }
    }
}

extern "C" void kernel_launch(void* const* d_in, const int* in_sizes, int n_in,
                              void* d_out, int out_size, void* d_ws, size_t ws_size,
                              hipStream_t stream) {
    const float* x    = (const float*)d_in[0];
    const int*   A    = (const int*)d_in[1];
    const float* Wp   = (const float*)d_in[2];
    const float* Watt = (const float*)d_in[3];
    const float* batt = (const float*)d_in[4];
    float* out = (float*)d_out;

    char* ws = (char*)d_ws;
    _Float16* x16 = (_Float16*)(ws + X16_OFF);
    _Float16* WT  = (_Float16*)(ws + WT_OFF);
    _Float16* xhT = (_Float16*)(ws + XHT_OFF);
    float* asrc = (float*)(ws + ASRC_OFF);
    float* adst = (float*)(ws + ADST_OFF);
    float* amax = (float*)(ws + AMAX_OFF);
    unsigned long long* mwT = (unsigned long long*)(ws + MW_OFF);

    k_prep<<<dim3(576), 256, 0, stream>>>(x, Wp, x16, WT);
    k_mask<<<dim3(512), 256, 0, stream>>>(A, mwT);
    k_proj<<<dim3(64, 8), 256, 0, stream>>>(x16, WT, Watt, xhT, asrc, adst);
    k_amax<<<dim3(16), 256, 0, stream>>>(adst, amax);
    k_attn<<<dim3(BB * HH * 32), 512, 0, stream>>>(xhT, asrc, adst, amax, mwT, batt, out);
}

// Round 5
// 66.342 us; speedup vs baseline: 3.4552x; 1.3206x over previous
//
#include <hip/hip_runtime.h>
#include <cstdint>
#include <cstddef>

#define NEG_SLOPE 0.2f
#define LOG2E 1.4426950408889634f

// Problem sizes (fixed by setup_inputs)
#define BB 2
#define NN 2048
#define DD 512
#define HH 8
#define KK 64   // head dim

typedef _Float16 half8 __attribute__((ext_vector_type(8)));
typedef _Float16 half4 __attribute__((ext_vector_type(4)));
typedef __fp16 fp16x2 __attribute__((ext_vector_type(2)));
typedef float floatx4 __attribute__((ext_vector_type(4)));

// Workspace layout (bytes)
#define X16T_OFF  ((size_t)0)            // x16 tiled: [256 mtile][64 chunk][16 m][8 k] f16 = 4 MB
#define WT_OFF    ((size_t)4194304)      // WT[o][d] f16 = 512 KB
#define XHT_OFF   ((size_t)4718592)      // xhT: [B*H][64][2048] f16 = 4 MB
#define ASRC_OFF  ((size_t)8912896)      // 32768 f32 = 128 KB
#define ADST_OFF  ((size_t)9043968)      // 32768 f32 = 128 KB
#define ADMAX_OFF ((size_t)9175040)      // [16 bh][128] f32 = 8 KB
#define MW_OFF    ((size_t)9183232)      // mwT: [B][32][2048] u64 = 1 MB

__device__ __forceinline__ float fexp2(float x) {
#if __has_builtin(__builtin_amdgcn_exp2f)
    return __builtin_amdgcn_exp2f(x);
#else
    return exp2f(x);
#endif
}

// ---------------- Kernel 1: x->f16 tiled, W transpose->f16, mask pack ---------
__global__ __launch_bounds__(256) void k_prep(const float* __restrict__ x,
                                              const float* __restrict__ Wp,
                                              const int* __restrict__ A,
                                              _Float16* __restrict__ x16t,
                                              _Float16* __restrict__ WT,
                                              unsigned long long* __restrict__ mwT) {
    __shared__ float tile[64][65];
    __shared__ unsigned long long mwt[32][8];
    const int tid = threadIdx.x;
    const int bi = blockIdx.x;
    if (bi < 256) {
        // x conversion to tiled layout: block covers rows bi*16..+15, all 512 k
        const int r = tid & 15, cg = tid >> 4;
        const float* srow = x + (size_t)(bi * 16 + r) * DD;
        _Float16* obase = x16t + ((size_t)bi * 64) * 128 + r * 8;
#pragma unroll
        for (int q = 0; q < 4; ++q) {
            const int chunk = q * 16 + cg;
            float4 v0 = *(const float4*)(srow + chunk * 8);
            float4 v1 = *(const float4*)(srow + chunk * 8 + 4);
            half8 hv;
            hv[0] = (_Float16)v0.x; hv[1] = (_Float16)v0.y;
            hv[2] = (_Float16)v0.z; hv[3] = (_Float16)v0.w;
            hv[4] = (_Float16)v1.x; hv[5] = (_Float16)v1.y;
            hv[6] = (_Float16)v1.z; hv[7] = (_Float16)v1.w;
            *(half8*)(obase + (size_t)chunk * 128) = hv;
        }
    } else if (bi < 320) {                // W transpose: 64 blocks of 64x64
        const int wb = bi - 256;
        const int d0 = (wb >> 3) * 64, o0 = (wb & 7) * 64;
        const int r = tid >> 2, cq = tid & 3;
#pragma unroll
        for (int qq = 0; qq < 4; ++qq) {
            float4 v = *(const float4*)&Wp[(size_t)(d0 + r) * DD + o0 + cq * 16 + qq * 4];
            tile[r][cq * 16 + qq * 4 + 0] = v.x;
            tile[r][cq * 16 + qq * 4 + 1] = v.y;
            tile[r][cq * 16 + qq * 4 + 2] = v.z;
            tile[r][cq * 16 + qq * 4 + 3] = v.w;
        }
        __syncthreads();
#pragma unroll
        for (int qq = 0; qq < 2; ++qq) {
            half8 hv;
#pragma unroll
            for (int e = 0; e < 8; ++e) hv[e] = (_Float16)tile[cq * 16 + qq * 8 + e][r];
            *(half8*)&WT[(size_t)(o0 + r) * DD + d0 + cq * 16 + qq * 8] = hv;
        }
    } else {                              // mask pack, transposed [b][c][n]
        const int mb = bi - 320;
        const int w = tid >> 6, lane = tid & 63;
        const int b = mb >> 8, n0 = (mb & 255) * 8;
#pragma unroll
        for (int rr = 0; rr < 2; ++rr) {
            const int rl = w * 2 + rr;
            const int* Arow = A + ((size_t)b * NN + n0 + rl) * NN;
#pragma unroll 4
            for (int c = 0; c < 32; ++c) {
                unsigned long long m = __ballot(Arow[c * 64 + lane] != 0);
                if (lane == 0) mwt[c][rl] = m;
            }
        }
        __syncthreads();
        const int c = tid >> 3, rl = tid & 7;
        mwT[((size_t)b * 32 + c) * NN + n0 + rl] = mwt[c][rl];
    }
}

// ---------------- Kernel 2: proj GEMM (f16 MFMA, B in swizzled LDS) -----------
// Grid (64 m-tiles, 8 heads), 256 thr / 4 waves. Wave owns 16 rows x 64 cols.
__global__ __launch_bounds__(256) void k_proj(const _Float16* __restrict__ x16t,
                                              const _Float16* __restrict__ WT,
                                              const float* __restrict__ Watt,
                                              _Float16* __restrict__ xhT,
                                              float* __restrict__ asrc,
                                              float* __restrict__ adst,
                                              float* __restrict__ admax) {
    __shared__ __align__(16) _Float16 bt[64 * 512];   // 64 KB, 16B-chunk XOR swizzle
    const int tid = threadIdx.x;
    const int m0 = blockIdx.x * 64;
    const int h  = blockIdx.y;
    // stage B: row = q*4 + wave, 1KB per row, chunk XOR (row&7)
    {
        const int cir = tid & 63, wv4 = tid >> 6;
        const char* gsrc = (const char*)(WT + (size_t)h * 64 * DD);
        char* lbase = (char*)bt;
#pragma unroll
        for (int q = 0; q < 16; ++q) {
            const int row = q * 4 + wv4;
            *(uint4*)(lbase + row * 1024 + ((cir ^ (row & 7)) * 16)) =
                *(const uint4*)(gsrc + (size_t)row * 1024 + cir * 16);
        }
    }
    __syncthreads();
    const int w = tid >> 6, l = tid & 63, li = l & 15, p = l >> 4;
    const char* bbase = (const char*)bt;
    const _Float16* abase = x16t + ((size_t)(blockIdx.x * 4 + w)) * 64 * 128 + li * 8;
    floatx4 acc[4] = {};
    for (int k0 = 0; k0 < DD; k0 += 32) {
        const int ch = (k0 >> 3) + p;
        half8 a = *(const half8*)(abase + (size_t)ch * 128);
#pragma unroll
        for (int ct = 0; ct < 4; ++ct) {
            const int row = ct * 16 + li;
            half8 bfr = *(const half8*)(bbase + row * 1024 + ((ch ^ (li & 7)) * 16));
            acc[ct] = __builtin_amdgcn_mfma_f32_16x16x32_f16(a, bfr, acc[ct], 0, 0, 0);
        }
    }
    const int b = m0 >> 11, n0 = m0 & (NN - 1);
    const int bh = b * HH + h;
#pragma unroll
    for (int ct = 0; ct < 4; ++ct) {
        half4 hv;
#pragma unroll
        for (int r = 0; r < 4; ++r) hv[r] = (_Float16)acc[ct][r];
        *(half4*)&xhT[((size_t)bh * 64 + ct * 16 + li) * NN + n0 + w * 16 + p * 4] = hv;
    }
    // fused a_src/a_dst + per-wave adst max partial
    float w1[4], w2[4];
#pragma unroll
    for (int ct = 0; ct < 4; ++ct) {
        w1[ct] = Watt[h * 128 + ct * 16 + li];
        w2[ct] = Watt[h * 128 + 64 + ct * 16 + li];
    }
    float mx = -1e30f;
#pragma unroll
    for (int r = 0; r < 4; ++r) {
        float s1 = 0.f, s2 = 0.f;
#pragma unroll
        for (int ct = 0; ct < 4; ++ct) { s1 += acc[ct][r] * w1[ct]; s2 += acc[ct][r] * w2[ct]; }
#pragma unroll
        for (int d = 1; d < 16; d <<= 1) { s1 += __shfl_xor(s1, d, 64); s2 += __shfl_xor(s2, d, 64); }
        mx = fmaxf(mx, s2);
        if (li == 0) {
            const int n = n0 + w * 16 + p * 4 + r;
            asrc[bh * NN + n] = s1;
            adst[bh * NN + n] = s2;
        }
    }
    mx = fmaxf(mx, __shfl_xor(mx, 16, 64));
    mx = fmaxf(mx, __shfl_xor(mx, 32, 64));
    if (l == 0) admax[bh * 128 + (blockIdx.x & 31) * 4 + w] = mx;
}

// ---------------- Kernel 3: masked softmax + PV via MFMA ----------------------
// 256 thr / 4 waves, 32-row i-tile, grid 1024. Wave w: parity g=w&1 (c mod 2),
// row-half wr=w>>1. T14: next tile prefetched to regs during compute.
__global__ __launch_bounds__(256) void k_attn(const _Float16* __restrict__ xhT,
                                              const float* __restrict__ asrc,
                                              const float* __restrict__ adst,
                                              const float* __restrict__ admax,
                                              const unsigned long long* __restrict__ mwT,
                                              const float* __restrict__ batt,
                                              float* __restrict__ out) {
    __shared__ __align__(16) _Float16 vt[2][4096];        // 2 parities x 8 KB
    __shared__ __align__(16) float adl[2][64];
    __shared__ unsigned long long mwl[2][32];
    __shared__ float accd_s[2][16];
    __shared__ float amx_s;

    const int tid = threadIdx.x;
    const int w = tid >> 6, l = tid & 63, li = l & 15, p = l >> 4;
    const int g = w & 1, wr = w >> 1;
    const int bid = blockIdx.x;
    const int bh = bid >> 6, it = bid & 63;
    const int b = bh >> 3, h = bh & (HH - 1);
    const int i0 = it * 32;

    const _Float16* vsrc = xhT + (size_t)bh * 64 * NN;
    const int pidx = wr * 64 + l;          // staging index within parity (0..127)
    const int sc = pidx & 7, sr = pidx >> 3;
    char* vtg = (char*)&vt[g][0];
    const int swz = (sc * 16) ^ ((sr & 7) << 4);

    // prefetch tile ci=0 (c = g) into regs
    uint4 rv0, rv1, rv2, rv3;
    float radl = 0.f; unsigned long long rmw = 0;
    {
        const int j0 = g * 64;
        rv0 = *(const uint4*)(vsrc + (size_t)(sr) * NN + j0 + sc * 8);
        rv1 = *(const uint4*)(vsrc + (size_t)(16 + sr) * NN + j0 + sc * 8);
        rv2 = *(const uint4*)(vsrc + (size_t)(32 + sr) * NN + j0 + sc * 8);
        rv3 = *(const uint4*)(vsrc + (size_t)(48 + sr) * NN + j0 + sc * 8);
        if (tid < 128) radl = adst[bh * NN + (tid >> 6) * 64 + (tid & 63)] * LOG2E;
        if (tid < 64)  rmw = mwT[((size_t)b * 32 + (tid >> 5)) * NN + i0 + (tid & 31)];
    }

    // reduce 128 adst-max partials (wave 0)
    if (w == 0) {
        float mx = fmaxf(admax[bh * 128 + l], admax[bh * 128 + 64 + l]);
#pragma unroll
        for (int d = 1; d < 64; d <<= 1) mx = fmaxf(mx, __shfl_xor(mx, d, 64));
        if (l == 0) amx_s = mx;
    }
    __syncthreads();
    const float am = amx_s;

    const float bbv = batt[h];
    const int i = i0 + wr * 16 + li;
    const float asb = (asrc[bh * NN + i] + bbv) * LOG2E;   // log2-domain scores
    const float tb = asb + am * LOG2E;
    const float Mi = fmaxf(tb, NEG_SLOPE * tb);            // row-max upper bound
    floatx4 acc[4] = {};
    floatx4 accd = {};
    half8 ones;
#pragma unroll
    for (int e = 0; e < 8; ++e) ones[e] = (_Float16)1.0f;

    for (int ci = 0; ci < 16; ++ci) {
        __syncthreads();                   // prev compute done reading vt/adl/mwl
        // commit prefetched tile
        *(uint4*)(vtg + (sr) * 128 + swz)      = rv0;
        *(uint4*)(vtg + (16 + sr) * 128 + swz) = rv1;
        *(uint4*)(vtg + (32 + sr) * 128 + swz) = rv2;
        *(uint4*)(vtg + (48 + sr) * 128 + swz) = rv3;
        if (tid < 128) adl[tid >> 6][tid & 63] = radl;
        if (tid < 64)  mwl[tid >> 5][tid & 31] = rmw;
        __syncthreads();
        // prefetch next tile (overlaps compute below)
        if (ci < 15) {
            const int cn = (ci + 1) * 2;
            const int j0n = (cn + g) * 64;
            rv0 = *(const uint4*)(vsrc + (size_t)(sr) * NN + j0n + sc * 8);
            rv1 = *(const uint4*)(vsrc + (size_t)(16 + sr) * NN + j0n + sc * 8);
            rv2 = *(const uint4*)(vsrc + (size_t)(32 + sr) * NN + j0n + sc * 8);
            rv3 = *(const uint4*)(vsrc + (size_t)(48 + sr) * NN + j0n + sc * 8);
            if (tid < 128) radl = adst[bh * NN + (cn + (tid >> 6)) * 64 + (tid & 63)] * LOG2E;
            if (tid < 64)  rmw = mwT[((size_t)b * 32 + cn + (tid >> 5)) * NN + i0 + (tid & 31)];
        }
        // compute current tile
        const unsigned long long mword = mwl[g][wr * 16 + li];
#pragma unroll
        for (int js = 0; js < 2; ++js) {
            const int shbase = js * 32 + p * 8;
            float4 A0 = *(const float4*)&adl[g][shbase];
            float4 A1 = *(const float4*)&adl[g][shbase + 4];
            const unsigned m8 = (unsigned)(mword >> shbase) & 0xFFu;
            float sv[8] = {A0.x, A0.y, A0.z, A0.w, A1.x, A1.y, A1.z, A1.w};
            float wv[8];
#pragma unroll
            for (int e = 0; e < 8; ++e) {
                float t = asb + sv[e];
                float s = fmaxf(t, NEG_SLOPE * t);
                float ev = fexp2(s - Mi);
                wv[e] = ((m8 >> e) & 1u) ? ev : 0.f;
            }
            union { fp16x2 h2[4]; half8 h8; } u;
            u.h2[0] = __builtin_amdgcn_cvt_pkrtz(wv[0], wv[1]);
            u.h2[1] = __builtin_amdgcn_cvt_pkrtz(wv[2], wv[3]);
            u.h2[2] = __builtin_amdgcn_cvt_pkrtz(wv[4], wv[5]);
            u.h2[3] = __builtin_amdgcn_cvt_pkrtz(wv[6], wv[7]);
            const half8 af = u.h8;
            accd = __builtin_amdgcn_mfma_f32_16x16x32_f16(af, ones, accd, 0, 0, 0);
#pragma unroll
            for (int ct = 0; ct < 4; ++ct) {
                const half8 bf = *(const half8*)(vtg + (ct * 16 + li) * 128 +
                                                 ((js * 64 + p * 16) ^ ((li & 7) << 4)));
                acc[ct] = __builtin_amdgcn_mfma_f32_16x16x32_f16(af, bf, acc[ct], 0, 0, 0);
            }
        }
    }

    // combine the two c-parities (pair = waves with same wr) via LDS
    __syncthreads();
    float* accs = (float*)&vt[0][0];       // 8 KB: [32 rows][64 cols]
    if (g == 1) {
#pragma unroll
        for (int ct = 0; ct < 4; ++ct)
#pragma unroll
            for (int r = 0; r < 4; ++r)
                accs[(wr * 16 + p * 4 + r) * 64 + ct * 16 + li] = acc[ct][r];
        if (li == 0) {
#pragma unroll
            for (int r = 0; r < 4; ++r) accd_s[wr][p * 4 + r] = accd[r];
        }
    }
    __syncthreads();
    if (g == 0) {
#pragma unroll
        for (int r = 0; r < 4; ++r) {
            const float d = accd[r] + accd_s[wr][p * 4 + r];
            const float inv = 1.f / fmaxf(d, 1e-30f);
            const int irow = i0 + wr * 16 + p * 4 + r;
            float* orow = out + ((size_t)b * NN + irow) * DD + h * KK;
#pragma unroll
            for (int ct = 0; ct < 4; ++ct) {
                const float v = (acc[ct][r] + accs[(wr * 16 + p * 4 + r) * 64 + ct * 16 + li]) * inv;
                orow[ct * 16 + li] = fmaxf(v, 0.f);
            }
        }
    }
}

extern "C" void kernel_launch(void* const* d_in, const int* in_sizes, int n_in,
                              void* d_out, int out_size, void* d_ws, size_t ws_size,
                              hipStream_t stream) {
    const float* x    = (const float*)d_in[0];
    const int*   A    = (const int*)d_in[1];
    const float* Wp   = (const float*)d_in[2];
    const float* Watt = (const float*)d_in[3];
    const float* batt = (const float*)d_in[4];
    float* out = (float*)d_out;

    char* ws = (char*)d_ws;
    _Float16* x16t = (_Float16*)(ws + X16T_OFF);
    _Float16* WT   = (_Float16*)(ws + WT_OFF);
    _Float16* xhT  = (_Float16*)(ws + XHT_OFF);
    float* asrc  = (float*)(ws + ASRC_OFF);
    float* adst  = (float*)(ws + ADST_OFF);
    float* admax = (float*)(ws + ADMAX_OFF);
    unsigned long long* mwT = (unsigned long long*)(ws + MW_OFF);

    k_prep<<<dim3(832), 256, 0, stream>>>(x, Wp, A, x16t, WT, mwT);
    k_proj<<<dim3(64, 8), 256, 0, stream>>>(x16t, WT, Watt, xhT, asrc, adst, admax);
    k_attn<<<dim3(BB * HH * 64), 256, 0, stream>>>(xhT, asrc, adst, admax, mwT, batt, out);
}